// Round 12
// baseline (128.241 us; speedup 1.0000x reference)
//
#include <hip/hip_runtime.h>
#include <hip/hip_bf16.h>
#include <stdint.h>

// ContrastiveLoss: N=8192, D=512 fp32 features, int labels {0,1}.
// out = mean_i [ (np_i * log(sum_exp_i) - sum_pos_i) / (np_i + 1e-8) ]
// R1: global_load_lds(16B) + XOR-swizzled LDS (bank-floor b128 reads).
// R2: upper-triangle tiles (2080). R3: collision-free partial slots.
// R5: fp8-e4m3 (x16 pre-scale; k pre-permuted identically for A/B).
// R7: XCD swizzle. R9: pipelined dbuf K-loop. R10: analytic sum_pos
//     (linear in sim): sp_i = 0.5*SC*(g_i.S + sig_i*g_i.T) - SC*|g_i|^2.
// R11 post-mortem: top dispatches are the harness's 256MB 0xAA ws-poison
//     fills (~45 us, untouchable) -> the constant ~70us "non-sim" floor.
// R12: consolidate controllable tail: colsum merged into the sim launch as
//     32 extra blocks writing per-block partials (no atomics -> no ST
//     zeroing, no cnt buffer); norm loses its serial label scan; final
//     sums 32 partials. 4 launches -> 3.

#define N_ROWS 8192
#define DIMF 512
#define DIMB 512
#define NB 64
#define NSIM 2080   // NB*(NB+1)/2
#define NCS 32      // colsum blocks
#define STSTRIDE 1056  // 512 S + 512 T + 1 cnt + pad
#define NSLOT 128
#define SIM_SCALE 0.0390625f  // 10 / 256  (features pre-scaled by 16)

typedef float f32x4 __attribute__((ext_vector_type(4)));
typedef int64_t i64x2 __attribute__((ext_vector_type(2)));

__device__ static inline void gload_lds16(const uint8_t* g, uint8_t* l) {
    __builtin_amdgcn_global_load_lds(
        (const __attribute__((address_space(1))) unsigned int*)g,
        (__attribute__((address_space(3))) unsigned int*)l, 16, 0, 0);
}

// 4 waves/block, one row per wave: fp32 sumsq -> scale by 16/norm -> fp8,
// k-permuted per 64B tile: orig (c,q) byte-group -> q*16 + c*8 (dot-invariant
// since A and B sides use the same permutation). Block 0 zeroes out[0].
__global__ __launch_bounds__(256) void norm_kernel(const float* __restrict__ x,
                                                   uint8_t* __restrict__ f8,
                                                   float* __restrict__ out) {
    const int wave = threadIdx.x >> 6, t = threadIdx.x & 63;
    const int row = blockIdx.x * 4 + wave;
    const float4* xr = (const float4*)(x + (size_t)row * DIMF);
    float4 v0 = xr[2 * t];
    float4 v1 = xr[2 * t + 1];
    float ss = v0.x * v0.x + v0.y * v0.y + v0.z * v0.z + v0.w * v0.w +
               v1.x * v1.x + v1.y * v1.y + v1.z * v1.z + v1.w * v1.w;
#pragma unroll
    for (int off = 32; off >= 1; off >>= 1) ss += __shfl_xor(ss, off, 64);
    float s = 16.0f / fmaxf(sqrtf(ss), 1e-12f);
    int lo = 0, hi = 0;
    lo = __builtin_amdgcn_cvt_pk_fp8_f32(v0.x * s, v0.y * s, lo, false);
    lo = __builtin_amdgcn_cvt_pk_fp8_f32(v0.z * s, v0.w * s, lo, true);
    hi = __builtin_amdgcn_cvt_pk_fp8_f32(v1.x * s, v1.y * s, hi, false);
    hi = __builtin_amdgcn_cvt_pk_fp8_f32(v1.z * s, v1.w * s, hi, true);
    int2 pk;
    pk.x = lo;
    pk.y = hi;
    const int pos = (t >> 3) * 64 + (t & 3) * 16 + ((t >> 2) & 1) * 8;
    *(int2*)(f8 + (size_t)row * DIMB + pos) = pk;
    if (blockIdx.x == 0 && threadIdx.x == 0) out[0] = 0.0f;
}

// Blocks [0,2080): 128x128 sim tile (4 waves 2x2, 4x4x2 MFMA 16x16x32 fp8,
//   BK=64B pipelined dbuf). Epilogue: sum_exp only -> PE slots.
// Blocks [2080,2112): colsum b = blk-2080: rows b*256..+255; per-thread
//   2 cols; plain-store partial S/T/count into STp[b] (no atomics).
__global__ __launch_bounds__(256, 4) void sim_kernel(const uint8_t* __restrict__ f8,
                                                     const int* __restrict__ lab,
                                                     float* __restrict__ PE,
                                                     float* __restrict__ STp) {
    if (blockIdx.x >= NSIM) {
        const int b = blockIdx.x - NSIM;
        const int t = threadIdx.x;
        const int c0 = (t >> 6) * 128 + (t & 63) * 2;
        const int r0 = b * 256;
        float s0 = 0, s1 = 0, t0 = 0, t1 = 0;
        int cl = 0;
#pragma unroll 4
        for (int r = 0; r < 256; ++r) {
            const int u = *(const uint16_t*)(f8 + (size_t)(r0 + r) * DIMB + c0);
            const float g0 = __builtin_amdgcn_cvt_f32_fp8(u, 0);
            const float g1 = __builtin_amdgcn_cvt_f32_fp8(u, 1);
            const int lb = lab[r0 + r];
            const float sg = lb ? 1.0f : -1.0f;
            s0 += g0;
            s1 += g1;
            t0 += sg * g0;
            t1 += sg * g1;
            cl += lb;
        }
        float* dst = STp + b * STSTRIDE;
        dst[c0] = s0;
        dst[c0 + 1] = s1;
        dst[512 + c0] = t0;
        dst[512 + c0 + 1] = t1;
        if (t == 0) dst[1024] = (float)cl;
        return;
    }

    __shared__ __align__(16) uint8_t sA[2][128 * 64];
    __shared__ __align__(16) uint8_t sB[2][128 * 64];

    // XCD-locality swizzle (2080 = 8 * 260); decode upper-triangle index.
    const int tblk = (blockIdx.x & 7) * 260 + (blockIdx.x >> 3);
    int bi = (int)(64.5f - sqrtf(64.5f * 64.5f - 2.0f * (float)tblk));
    while (bi * (129 - bi) / 2 > tblk) --bi;
    while ((bi + 1) * (128 - bi) / 2 <= tblk) ++bi;
    const int bj = bi + (tblk - bi * (129 - bi) / 2);
    const bool diag = (bi == bj);

    const int t = threadIdx.x;
    const int iBase = bi * 128, jBase = bj * 128;
    const int lane = t & 63, wave = t >> 6;
    const int wm = wave >> 1, wn = wave & 1;
    const int lrow = lane & 15, quad = lane >> 4;

    const int sub = lane >> 2;
    const int lu = (lane & 3) ^ ((sub >> 1) & 3);
    const size_t gA0 = (size_t)(iBase + wave * 32 + sub) * DIMB + lu * 16;
    const size_t gB0 = (size_t)(jBase + wave * 32 + sub) * DIMB + lu * 16;

    f32x4 acc[4][4] = {};

#pragma unroll
    for (int c = 0; c < 2; ++c) {
        gload_lds16(f8 + gA0 + (size_t)(c * 16) * DIMB, sA[0] + (wave * 32 + c * 16) * 64);
        gload_lds16(f8 + gB0 + (size_t)(c * 16) * DIMB, sB[0] + (wave * 32 + c * 16) * 64);
    }

#pragma unroll
    for (int kk = 0; kk < 8; ++kk) {
        const int cur = kk & 1;
        __syncthreads();
        if (kk < 7) {
#pragma unroll
            for (int c = 0; c < 2; ++c) {
                gload_lds16(f8 + gA0 + (size_t)(c * 16) * DIMB + (kk + 1) * 64,
                            sA[cur ^ 1] + (wave * 32 + c * 16) * 64);
                gload_lds16(f8 + gB0 + (size_t)(c * 16) * DIMB + (kk + 1) * 64,
                            sB[cur ^ 1] + (wave * 32 + c * 16) * 64);
            }
        }
        const int pu = (quad ^ ((lrow >> 1) & 3)) * 16;
        i64x2 af[4], bfr[4];
#pragma unroll
        for (int m = 0; m < 4; ++m)
            af[m] = *(const i64x2*)(sA[cur] + (wm * 64 + m * 16 + lrow) * 64 + pu);
#pragma unroll
        for (int n = 0; n < 4; ++n)
            bfr[n] = *(const i64x2*)(sB[cur] + (wn * 64 + n * 16 + lrow) * 64 + pu);
#pragma unroll
        for (int m = 0; m < 4; ++m)
#pragma unroll
            for (int n = 0; n < 4; ++n) {
                acc[m][n] = __builtin_amdgcn_mfma_f32_16x16x32_fp8_fp8(
                    af[m].x, bfr[n].x, acc[m][n], 0, 0, 0);
                acc[m][n] = __builtin_amdgcn_mfma_f32_16x16x32_fp8_fp8(
                    af[m].y, bfr[n].y, acc[m][n], 0, 0, 0);
            }
    }

    // Epilogue (sum_exp only). C/D layout: col = lane&15, row = quad*4 + reg.
    const int slotR = 2 * bj + wn;  // rows of iBase
    const int slotC = 2 * bi + wm;  // cols of jBase
    float sec[4] = {0, 0, 0, 0};

#pragma unroll
    for (int m = 0; m < 4; ++m) {
        float rE[4];
#pragma unroll
        for (int e = 0; e < 4; ++e) {
            const int r = wm * 64 + m * 16 + quad * 4 + e;
            float se = 0.0f;
            if (diag) {
                const int i = iBase + r;
#pragma unroll
                for (int n = 0; n < 4; ++n) {
                    const int j = jBase + wn * 64 + n * 16 + lrow;
                    if (j != i) se += __expf(acc[m][n][e] * SIM_SCALE);
                }
            } else {
#pragma unroll
                for (int n = 0; n < 4; ++n) {
                    const float ex = __expf(acc[m][n][e] * SIM_SCALE);
                    se += ex;
                    sec[n] += ex;
                }
            }
#pragma unroll
            for (int off = 8; off >= 1; off >>= 1) se += __shfl_xor(se, off, 16);
            rE[e] = se;
        }
        if (lrow == 0) {
            const size_t o = (size_t)slotR * N_ROWS + iBase + wm * 64 + m * 16 + quad * 4;
            float4 vE = {rE[0], rE[1], rE[2], rE[3]};
            *(float4*)&PE[o] = vE;
        }
    }

    if (!diag) {
#pragma unroll
        for (int n = 0; n < 4; ++n) {
            sec[n] += __shfl_xor(sec[n], 16, 64);
            sec[n] += __shfl_xor(sec[n], 32, 64);
        }
        if (quad == 0) {
#pragma unroll
            for (int n = 0; n < 4; ++n)
                PE[(size_t)slotC * N_ROWS + jBase + wn * 64 + n * 16 + lrow] = sec[n];
        }
    }
}

// 128 blocks x 64 rows. Sum 32 S/T/cnt partials into LDS; then thread
// (row = b*64 + t>>2, quarter q = t&3): d1 = g_i.S, d2 = g_i.T,
// sii = |g_i|^2 over 128 cols + 32 PE slots; fold quarters; loss;
// block-reduce; atomicAdd mean into out.
__global__ __launch_bounds__(256) void final_kernel(const float* __restrict__ PE,
                                                    const uint8_t* __restrict__ f8,
                                                    const int* __restrict__ lab,
                                                    const float* __restrict__ STp,
                                                    float* __restrict__ out) {
    __shared__ float sS[512], sT[512], sh[4];
    __shared__ float scnt;
    const int t = threadIdx.x;
    {
        float a0 = 0, a1 = 0, b0 = 0, b1 = 0;
#pragma unroll 8
        for (int p = 0; p < NCS; ++p) {
            const float* base = STp + p * STSTRIDE;
            a0 += base[2 * t];
            a1 += base[2 * t + 1];
            b0 += base[512 + 2 * t];
            b1 += base[512 + 2 * t + 1];
        }
        sS[2 * t] = a0;
        sS[2 * t + 1] = a1;
        sT[2 * t] = b0;
        sT[2 * t + 1] = b1;
        if (t == 0) {
            float c = 0;
#pragma unroll 8
            for (int p = 0; p < NCS; ++p) c += STp[p * STSTRIDE + 1024];
            scnt = c;
        }
    }
    __syncthreads();

    const int r = blockIdx.x * 64 + (t >> 2);
    const int q = t & 3;
    const uint8_t* rowp = f8 + (size_t)r * DIMB + q * 128;

    float d1 = 0, d2 = 0, sii = 0;
#pragma unroll
    for (int c = 0; c < 32; ++c) {
        const int u = *(const int*)(rowp + c * 4);
        const int base = q * 128 + c * 4;
        const float g0 = __builtin_amdgcn_cvt_f32_fp8(u, 0);
        const float g1 = __builtin_amdgcn_cvt_f32_fp8(u, 1);
        const float g2 = __builtin_amdgcn_cvt_f32_fp8(u, 2);
        const float g3 = __builtin_amdgcn_cvt_f32_fp8(u, 3);
        d1 += g0 * sS[base] + g1 * sS[base + 1] + g2 * sS[base + 2] + g3 * sS[base + 3];
        d2 += g0 * sT[base] + g1 * sT[base + 1] + g2 * sT[base + 2] + g3 * sT[base + 3];
        sii += g0 * g0 + g1 * g1 + g2 * g2 + g3 * g3;
    }
    float se = 0.0f;
#pragma unroll 8
    for (int s = 32 * q; s < 32 * q + 32; ++s) se += PE[(size_t)s * N_ROWS + r];

    // fold the 4 quarter-threads (same wave, lanes t, t^1, t^2)
#pragma unroll
    for (int off = 2; off >= 1; off >>= 1) {
        d1 += __shfl_xor(d1, off, 64);
        d2 += __shfl_xor(d2, off, 64);
        sii += __shfl_xor(sii, off, 64);
        se += __shfl_xor(se, off, 64);
    }

    float local = 0.0f;
    if (q == 0) {
        const float c1 = scnt;
        const int li = lab[r];
        const float np = (li ? c1 : (float)N_ROWS - c1) - 1.0f;
        const float sg = li ? 1.0f : -1.0f;
        const float sp = 0.5f * SIM_SCALE * (d1 + sg * d2) - SIM_SCALE * sii;
        local = (np * __logf(se) - sp) / (np + 1e-8f);
    }
    const int lane = t & 63, w = t >> 6;
#pragma unroll
    for (int off = 32; off >= 1; off >>= 1) local += __shfl_xor(local, off, 64);
    if (lane == 0) sh[w] = local;
    __syncthreads();
    if (threadIdx.x == 0)
        atomicAdd(out, (sh[0] + sh[1] + sh[2] + sh[3]) * (1.0f / (float)N_ROWS));
}

extern "C" void kernel_launch(void* const* d_in, const int* in_sizes, int n_in,
                              void* d_out, int out_size, void* d_ws, size_t ws_size,
                              hipStream_t stream) {
    const float* features = (const float*)d_in[0];
    const int* labels = (const int*)d_in[1];
    float* out = (float*)d_out;

    char* ws = (char*)d_ws;
    uint8_t* f8 = (uint8_t*)ws;                              // 4 MiB
    float* PE = (float*)(ws + (size_t)N_ROWS * DIMB);        // 4 MiB
    float* STp = PE + (size_t)NSLOT * N_ROWS;                // 132 KiB

    norm_kernel<<<N_ROWS / 4, 256, 0, stream>>>(features, f8, out);
    sim_kernel<<<NSIM + NCS, 256, 0, stream>>>(f8, labels, PE, STp);
    final_kernel<<<128, 256, 0, stream>>>(PE, f8, labels, STp, out);
}

// Round 13
// 117.829 us; speedup vs baseline: 1.0884x; 1.0884x over previous
//
#include <hip/hip_runtime.h>
#include <hip/hip_bf16.h>
#include <stdint.h>

// ContrastiveLoss: N=8192, D=512 fp32 features, int labels {0,1}.
// out = mean_i [ (np_i * log(sum_exp_i) - sum_pos_i) / (np_i + 1e-8) ]
// R1: global_load_lds(16B) + XOR-swizzled LDS (bank-floor b128 reads).
// R2: upper-triangle tiles (2080). R3: collision-free partial slots.
// R5: fp8-e4m3 (x16 pre-scale; k pre-permuted identically for A/B).
// R7: XCD swizzle. R9: pipelined dbuf K-loop -> sim 46.4 us (champion 121).
// R10-R12 post-mortem: analytic sum_pos + colsum was a net LOSS (sim is
//     insensitive to epilogue VALU; colsum tail/launch cost ~4-7 us).
// R13: revert to R9 champion; PE/PP transposed to [row][slot] so final's
//     slot-sum reads are contiguous 512B/row (was 32KB-strided); final
//     parallelized to 128 blocks. Sim stores become slot-strided scatters
//     (small, L2-absorbed).

#define N_ROWS 8192
#define DIMF 512
#define DIMB 512
#define NB 64
#define NSLOT 128
#define SIM_SCALE 0.0390625f  // 10 / 256  (features pre-scaled by 16)

typedef float f32x4 __attribute__((ext_vector_type(4)));
typedef int64_t i64x2 __attribute__((ext_vector_type(2)));

__device__ static inline void gload_lds16(const uint8_t* g, uint8_t* l) {
    __builtin_amdgcn_global_load_lds(
        (const __attribute__((address_space(1))) unsigned int*)g,
        (__attribute__((address_space(3))) unsigned int*)l, 16, 0, 0);
}

// 4 waves/block, one row per wave: fp32 sumsq -> scale by 16/norm -> fp8,
// k-permuted per 64B tile: orig (c,q) byte-group -> q*16 + c*8 (dot-invariant
// since A and B sides use the same permutation). Block 0 zeroes out[0].
__global__ __launch_bounds__(256) void norm_kernel(const float* __restrict__ x,
                                                   uint8_t* __restrict__ f8,
                                                   float* __restrict__ out) {
    const int wave = threadIdx.x >> 6, t = threadIdx.x & 63;
    const int row = blockIdx.x * 4 + wave;
    const float4* xr = (const float4*)(x + (size_t)row * DIMF);
    float4 v0 = xr[2 * t];
    float4 v1 = xr[2 * t + 1];
    float ss = v0.x * v0.x + v0.y * v0.y + v0.z * v0.z + v0.w * v0.w +
               v1.x * v1.x + v1.y * v1.y + v1.z * v1.z + v1.w * v1.w;
#pragma unroll
    for (int off = 32; off >= 1; off >>= 1) ss += __shfl_xor(ss, off, 64);
    float s = 16.0f / fmaxf(sqrtf(ss), 1e-12f);
    int lo = 0, hi = 0;
    lo = __builtin_amdgcn_cvt_pk_fp8_f32(v0.x * s, v0.y * s, lo, false);
    lo = __builtin_amdgcn_cvt_pk_fp8_f32(v0.z * s, v0.w * s, lo, true);
    hi = __builtin_amdgcn_cvt_pk_fp8_f32(v1.x * s, v1.y * s, hi, false);
    hi = __builtin_amdgcn_cvt_pk_fp8_f32(v1.z * s, v1.w * s, hi, true);
    int2 pk;
    pk.x = lo;
    pk.y = hi;
    const int pos = (t >> 3) * 64 + (t & 3) * 16 + ((t >> 2) & 1) * 8;
    *(int2*)(f8 + (size_t)row * DIMB + pos) = pk;
    if (blockIdx.x == 0 && threadIdx.x == 0) out[0] = 0.0f;
}

// 128x128 tile/block (4 waves 2x2, each 64x64 via 4x4x2 MFMA 16x16x32 fp8).
// BK=64B, double-buffered, pipelined: batch kk+1 issued after barrier kk,
// before compute kk -> barrier drains a compute-phase-old batch (free).
// PE/PP are [row][slot] (slot = 2*bj+wn for rows, 2*bi+wm for cols).
__global__ __launch_bounds__(256, 4) void sim_kernel(const uint8_t* __restrict__ f8,
                                                     const int* __restrict__ lab,
                                                     float* __restrict__ PE,
                                                     float* __restrict__ PP) {
    __shared__ __align__(16) uint8_t sA[2][128 * 64];
    __shared__ __align__(16) uint8_t sB[2][128 * 64];

    // XCD-locality swizzle (2080 = 8 * 260); decode upper-triangle index.
    const int tblk = (blockIdx.x & 7) * 260 + (blockIdx.x >> 3);
    int bi = (int)(64.5f - sqrtf(64.5f * 64.5f - 2.0f * (float)tblk));
    while (bi * (129 - bi) / 2 > tblk) --bi;
    while ((bi + 1) * (128 - bi) / 2 <= tblk) ++bi;
    const int bj = bi + (tblk - bi * (129 - bi) / 2);
    const bool diag = (bi == bj);

    const int t = threadIdx.x;
    const int iBase = bi * 128, jBase = bj * 128;
    const int lane = t & 63, wave = t >> 6;
    const int wm = wave >> 1, wn = wave & 1;
    const int lrow = lane & 15, quad = lane >> 4;

    const int sub = lane >> 2;
    const int lu = (lane & 3) ^ ((sub >> 1) & 3);
    const size_t gA0 = (size_t)(iBase + wave * 32 + sub) * DIMB + lu * 16;
    const size_t gB0 = (size_t)(jBase + wave * 32 + sub) * DIMB + lu * 16;

    f32x4 acc[4][4] = {};

#pragma unroll
    for (int c = 0; c < 2; ++c) {
        gload_lds16(f8 + gA0 + (size_t)(c * 16) * DIMB, sA[0] + (wave * 32 + c * 16) * 64);
        gload_lds16(f8 + gB0 + (size_t)(c * 16) * DIMB, sB[0] + (wave * 32 + c * 16) * 64);
    }

#pragma unroll
    for (int kk = 0; kk < 8; ++kk) {
        const int cur = kk & 1;
        __syncthreads();
        if (kk < 7) {
#pragma unroll
            for (int c = 0; c < 2; ++c) {
                gload_lds16(f8 + gA0 + (size_t)(c * 16) * DIMB + (kk + 1) * 64,
                            sA[cur ^ 1] + (wave * 32 + c * 16) * 64);
                gload_lds16(f8 + gB0 + (size_t)(c * 16) * DIMB + (kk + 1) * 64,
                            sB[cur ^ 1] + (wave * 32 + c * 16) * 64);
            }
        }
        const int pu = (quad ^ ((lrow >> 1) & 3)) * 16;
        i64x2 af[4], bfr[4];
#pragma unroll
        for (int m = 0; m < 4; ++m)
            af[m] = *(const i64x2*)(sA[cur] + (wm * 64 + m * 16 + lrow) * 64 + pu);
#pragma unroll
        for (int n = 0; n < 4; ++n)
            bfr[n] = *(const i64x2*)(sB[cur] + (wn * 64 + n * 16 + lrow) * 64 + pu);
#pragma unroll
        for (int m = 0; m < 4; ++m)
#pragma unroll
            for (int n = 0; n < 4; ++n) {
                acc[m][n] = __builtin_amdgcn_mfma_f32_16x16x32_fp8_fp8(
                    af[m].x, bfr[n].x, acc[m][n], 0, 0, 0);
                acc[m][n] = __builtin_amdgcn_mfma_f32_16x16x32_fp8_fp8(
                    af[m].y, bfr[n].y, acc[m][n], 0, 0, 0);
            }
    }

    // Register-only epilogue. C/D layout: col=lane&15, row=quad*4+reg.
    int labj[4];
#pragma unroll
    for (int n = 0; n < 4; ++n) labj[n] = lab[jBase + wn * 64 + n * 16 + lrow];

    const int slotR = 2 * bj + wn;  // rows of iBase
    const int slotC = 2 * bi + wm;  // cols of jBase
    float sec[4] = {0, 0, 0, 0}, spc[4] = {0, 0, 0, 0};

#pragma unroll
    for (int m = 0; m < 4; ++m) {
        float rE[4], rP[4];
#pragma unroll
        for (int e = 0; e < 4; ++e) {
            const int r = wm * 64 + m * 16 + quad * 4 + e;
            const int i = iBase + r;
            const int labi = lab[i];
            float se = 0.0f, sp = 0.0f;
            if (diag) {
#pragma unroll
                for (int n = 0; n < 4; ++n) {
                    const int j = jBase + wn * 64 + n * 16 + lrow;
                    const float sim = acc[m][n][e] * SIM_SCALE;
                    if (j != i) {
                        se += __expf(sim);
                        if (labj[n] == labi) sp += sim;
                    }
                }
            } else {
#pragma unroll
                for (int n = 0; n < 4; ++n) {
                    const float sim = acc[m][n][e] * SIM_SCALE;
                    const float ex = __expf(sim);
                    se += ex;
                    sec[n] += ex;
                    if (labj[n] == labi) {
                        sp += sim;
                        spc[n] += sim;
                    }
                }
            }
#pragma unroll
            for (int off = 8; off >= 1; off >>= 1) {
                se += __shfl_xor(se, off, 16);
                sp += __shfl_xor(sp, off, 16);
            }
            rE[e] = se;
            rP[e] = sp;
        }
        if (lrow == 0) {
            const int rb = iBase + wm * 64 + m * 16 + quad * 4;
#pragma unroll
            for (int e = 0; e < 4; ++e) {
                PE[(size_t)(rb + e) * NSLOT + slotR] = rE[e];
                PP[(size_t)(rb + e) * NSLOT + slotR] = rP[e];
            }
        }
    }

    if (!diag) {
#pragma unroll
        for (int n = 0; n < 4; ++n) {
            sec[n] += __shfl_xor(sec[n], 16, 64);
            sec[n] += __shfl_xor(sec[n], 32, 64);
            spc[n] += __shfl_xor(spc[n], 16, 64);
            spc[n] += __shfl_xor(spc[n], 32, 64);
        }
        if (quad == 0) {
#pragma unroll
            for (int n = 0; n < 4; ++n) {
                const int j = jBase + wn * 64 + n * 16 + lrow;
                PE[(size_t)j * NSLOT + slotC] = sec[n];
                PP[(size_t)j * NSLOT + slotC] = spc[n];
            }
        }
    }
}

// 128 blocks x 64 rows. Per-block full label count (32 coalesced iters);
// thread (row = b*64 + t>>2, quarter q = t&3) sums PE/PP[row][32q..32q+32)
// (contiguous 128B); fold quarters by shuffle; loss; block-reduce; atomicAdd.
__global__ __launch_bounds__(256) void final_kernel(const float* __restrict__ PE,
                                                    const float* __restrict__ PP,
                                                    const int* __restrict__ lab,
                                                    float* __restrict__ out) {
    __shared__ float sh[4];
    __shared__ float shc;
    const int t = threadIdx.x;
    const int lane = t & 63, w = t >> 6;

    int cl = 0;
#pragma unroll 8
    for (int s = t; s < N_ROWS; s += 256) cl += lab[s];
#pragma unroll
    for (int off = 32; off >= 1; off >>= 1) cl += __shfl_xor(cl, off, 64);
    if (lane == 0) sh[w] = (float)cl;
    __syncthreads();
    if (t == 0) shc = sh[0] + sh[1] + sh[2] + sh[3];
    __syncthreads();
    const float c1 = shc;

    const int r = blockIdx.x * 64 + (t >> 2);
    const int q = t & 3;
    const float4* pe = (const float4*)(PE + (size_t)r * NSLOT + 32 * q);
    const float4* pp = (const float4*)(PP + (size_t)r * NSLOT + 32 * q);
    float se = 0.0f, sp = 0.0f;
#pragma unroll
    for (int v = 0; v < 8; ++v) {
        const float4 e4 = pe[v];
        const float4 p4 = pp[v];
        se += e4.x + e4.y + e4.z + e4.w;
        sp += p4.x + p4.y + p4.z + p4.w;
    }
#pragma unroll
    for (int off = 2; off >= 1; off >>= 1) {
        se += __shfl_xor(se, off, 64);
        sp += __shfl_xor(sp, off, 64);
    }

    float local = 0.0f;
    if (q == 0) {
        const int li = lab[r];
        const float np = (li ? c1 : (float)N_ROWS - c1) - 1.0f;
        local = (np * __logf(se) - sp) / (np + 1e-8f);
    }
#pragma unroll
    for (int off = 32; off >= 1; off >>= 1) local += __shfl_xor(local, off, 64);
    __syncthreads();
    if (lane == 0) sh[w] = local;
    __syncthreads();
    if (t == 0)
        atomicAdd(out, (sh[0] + sh[1] + sh[2] + sh[3]) * (1.0f / (float)N_ROWS));
}

extern "C" void kernel_launch(void* const* d_in, const int* in_sizes, int n_in,
                              void* d_out, int out_size, void* d_ws, size_t ws_size,
                              hipStream_t stream) {
    const float* features = (const float*)d_in[0];
    const int* labels = (const int*)d_in[1];
    float* out = (float*)d_out;

    char* ws = (char*)d_ws;
    uint8_t* f8 = (uint8_t*)ws;                              // 4 MiB
    float* PE = (float*)(ws + (size_t)N_ROWS * DIMB);        // 4 MiB [row][slot]
    float* PP = PE + (size_t)N_ROWS * NSLOT;                 // 4 MiB [row][slot]

    norm_kernel<<<N_ROWS / 4, 256, 0, stream>>>(features, f8, out);
    sim_kernel<<<NB * (NB + 1) / 2, 256, 0, stream>>>(f8, labels, PE, PP);
    final_kernel<<<128, 256, 0, stream>>>(PE, PP, labels, out);
}